// Round 6
// baseline (248.465 us; speedup 1.0000x reference)
//
#include <hip/hip_runtime.h>

#define NT 256

// ---------------------------------------------------------------------------
// LDS layout: two 32 KB buffers (float4[2048] each), 64 KB total -> 2 blocks/CU.
// Physical mapping at float4 granularity: F = f ^ ((f>>3)&7)  (involution).
// b128 accesses address whole float4 units -> no intra-unit order assumption.
// Bank check (by hand): ex2 b128: F%8 = u ^ (m2&7) -> 8 consecutive lanes hit 8
// distinct bank-groups (conflict-free). ex1w b64: 2-way. ex1r/ex2w b64: 2-way.
// 2-way is free on gfx950 (m136).
// ---------------------------------------------------------------------------

// 16-point DFT in registers: v[k] = sum_j v[j] * w16^{jk}, w16 = e^{-2pi i/16}
// (INV=true: conjugated; unnormalized). Natural order in/out.  [verified R3/R5]
template<bool INV>
__device__ __forceinline__ void dft16(float* vr, float* vi) {
    constexpr float C1 = 0.9238795325112867f;   // cos(pi/8)
    constexpr float S1 = 0.3826834323650898f;   // sin(pi/8)
    constexpr float HF = 0.7071067811865476f;
    const float WR[10] = {1.f,  C1,  HF,  S1, 0.f, 0.f, -HF, 0.f, 0.f, -C1};
    const float WI[10] = {0.f, -S1, -HF, -C1, -1.f, 0.f, -HF, 0.f, 0.f,  S1};

    float ar[16], ai[16];
    #pragma unroll
    for (int jl = 0; jl < 4; ++jl) {
        float x0r = vr[jl],      x0i = vi[jl];
        float x1r = vr[jl + 4],  x1i = vi[jl + 4];
        float x2r = vr[jl + 8],  x2i = vi[jl + 8];
        float x3r = vr[jl + 12], x3i = vi[jl + 12];
        float t0r = x0r + x2r, t0i = x0i + x2i;
        float t1r = x0r - x2r, t1i = x0i - x2i;
        float t2r = x1r + x3r, t2i = x1i + x3i;
        float t3r = x1r - x3r, t3i = x1i - x3i;
        ar[jl]     = t0r + t2r;  ai[jl]     = t0i + t2i;
        ar[jl + 8] = t0r - t2r;  ai[jl + 8] = t0i - t2i;
        if (!INV) {
            ar[jl + 4]  = t1r + t3i;  ai[jl + 4]  = t1i - t3r;  // t1 - i*t3
            ar[jl + 12] = t1r - t3i;  ai[jl + 12] = t1i + t3r;  // t1 + i*t3
        } else {
            ar[jl + 4]  = t1r - t3i;  ai[jl + 4]  = t1i + t3r;
            ar[jl + 12] = t1r + t3i;  ai[jl + 12] = t1i - t3r;
        }
    }
    #pragma unroll
    for (int k4 = 1; k4 < 4; ++k4) {
        #pragma unroll
        for (int jl = 1; jl < 4; ++jl) {
            const int e = jl * k4;
            float wr = WR[e];
            float wi = INV ? -WI[e] : WI[e];
            const int id = jl + 4 * k4;
            float xr = ar[id], xi = ai[id];
            ar[id] = xr * wr - xi * wi;
            ai[id] = xr * wi + xi * wr;
        }
    }
    #pragma unroll
    for (int k4 = 0; k4 < 4; ++k4) {
        float x0r = ar[4*k4 + 0], x0i = ai[4*k4 + 0];
        float x1r = ar[4*k4 + 1], x1i = ai[4*k4 + 1];
        float x2r = ar[4*k4 + 2], x2i = ai[4*k4 + 2];
        float x3r = ar[4*k4 + 3], x3i = ai[4*k4 + 3];
        float t0r = x0r + x2r, t0i = x0i + x2i;
        float t1r = x0r - x2r, t1i = x0i - x2i;
        float t2r = x1r + x3r, t2i = x1i + x3i;
        float t3r = x1r - x3r, t3i = x1i - x3i;
        vr[k4]     = t0r + t2r;  vi[k4]     = t0i + t2i;
        vr[k4 + 8] = t0r - t2r;  vi[k4 + 8] = t0i - t2i;
        if (!INV) {
            vr[k4 + 4]  = t1r + t3i;  vi[k4 + 4]  = t1i - t3r;
            vr[k4 + 12] = t1r - t3i;  vi[k4 + 12] = t1i + t3r;
        } else {
            vr[k4 + 4]  = t1r - t3i;  vi[k4 + 4]  = t1i + t3r;
            vr[k4 + 12] = t1r + t3i;  vi[k4 + 12] = t1i - t3r;
        }
    }
}

__device__ __forceinline__ void cmul_ip(float& xr, float& xi, float wr, float wi) {
    float r = xr * wr - xi * wi;
    float i = xr * wi + xi * wr;
    xr = r; xi = i;
}

// v[e] *= w^e for e=1..15, applied to TWO FFTs sharing one power chain
// (two w^2-stepping chains for shorter serial latency).
__device__ __forceinline__ void apply_tw_dual(float* vr1, float* vi1,
                                              float* vr2, float* vi2,
                                              float wr, float wi) {
    const float w2r = wr * wr - wi * wi;
    const float w2i = 2.0f * wr * wi;
    float aor = wr,  aoi = wi;    // odd powers
    float aer = w2r, aei = w2i;   // even powers
    #pragma unroll
    for (int e = 1; e < 16; e += 2) {
        cmul_ip(vr1[e], vi1[e], aor, aoi);
        cmul_ip(vr2[e], vi2[e], aor, aoi);
        if (e + 1 < 16) {
            cmul_ip(vr1[e + 1], vi1[e + 1], aer, aei);
            cmul_ip(vr2[e + 1], vi2[e + 1], aer, aei);
        }
        if (e + 2 < 16) {
            float nr = aor * w2r - aoi * w2i, ni = aor * w2i + aoi * w2r;
            aor = nr; aoi = ni;
            nr = aer * w2r - aei * w2i; ni = aer * w2i + aei * w2r;
            aer = nr; aei = ni;
        }
    }
}

__global__ __launch_bounds__(NT, 2) void spectral_circulant_r16x2(
    const float* __restrict__ x,
    const float* __restrict__ w_real,
    const float* __restrict__ w_imag,
    const float* __restrict__ bias_p,
    float* __restrict__ out)
{
    __shared__ __align__(16) float4 lds4[4096];      // 64 KB = 2 buffers of 2048 f4
    float2* const p2 = (float2*)lds4;                // physical float2 view
    // buffer 2: +2048 float4 units = +4096 float2 units

    const int t   = threadIdx.x;
    const int blk = blockIdx.x;                      // rows 4blk .. 4blk+3

    float vr1[16], vi1[16], vr2[16], vi2[16];

    // ---- load 4 rows: FFT1 = rowA + i*rowB, FFT2 = rowC + i*rowD ----
    const float* __restrict__ xa = x + (size_t)(4 * blk) * 4096;
    #pragma unroll
    for (int j = 0; j < 16; ++j) {
        vr1[j] = xa[(j << 8) + t];
        vi1[j] = xa[4096 + (j << 8) + t];
    }
    #pragma unroll
    for (int j = 0; j < 16; ++j) {
        vr2[j] = xa[8192 + (j << 8) + t];
        vi2[j] = xa[12288 + (j << 8) + t];
    }

    // ---- stage A: DFT16 over j; twiddle W4096^{t*a} (shared chain) ----
    dft16<false>(vr1, vi1);
    dft16<false>(vr2, vi2);
    float sA, cA;
    __sincosf((float)t * -1.5339807878856412e-3f, &sA, &cA);  // -2pi/4096
    apply_tw_dual(vr1, vi1, vr2, vi2, cA, sA);

    // ---- exchange 1 write: logical l = 256a + t; phys f2 = 256a + e1w ----
    const int e1w = 2 * (((t >> 1) ^ ((t >> 4) & 7))) + (t & 1);
    #pragma unroll
    for (int a = 0; a < 16; ++a) {
        p2[256 * a + e1w]        = make_float2(vr1[a], vi1[a]);
        p2[4096 + 256 * a + e1w] = make_float2(vr2[a], vi2[a]);
    }
    __syncthreads();

    const int ax = t >> 4;           // upper digit owned from here on
    const int m2 = t & 15;           // lower digit
    const int mh = m2 >> 1, ml = m2 & 1;
    const int bx = 256 * ax + ml;    // per-thread b64 set: bx + 16q + 2*(mh^(q&7))

    // ---- exchange 1 read: logical l = 256ax + 16q + m2 ----
    #pragma unroll
    for (int q = 0; q < 16; ++q) {
        const int ad = bx + 16 * q + 2 * (mh ^ (q & 7));
        float2 v1 = p2[ad];        vr1[q] = v1.x; vi1[q] = v1.y;
        float2 v2 = p2[4096 + ad]; vr2[q] = v2.x; vi2[q] = v2.y;
    }

    // ---- stage B: DFT16 over q; twiddle W256^{m2*b} (shared chain) ----
    dft16<false>(vr1, vi1);
    dft16<false>(vr2, vi2);
    float sB, cB;
    __sincosf((float)m2 * -2.454369260617026e-2f, &sB, &cB);  // -2pi/256
    apply_tw_dual(vr1, vi1, vr2, vi2, cB, sB);

    // ---- exchange 2 write: same per-thread set (wave-local exchange within
    // 16 consecutive threads -> per-wave in-order DS pipe, no block barrier) ----
    #pragma unroll
    for (int b = 0; b < 16; ++b) {
        const int ad = bx + 16 * b + 2 * (mh ^ (b & 7));
        p2[ad]        = make_float2(vr1[b], vi1[b]);
        p2[4096 + ad] = make_float2(vr2[b], vi2[b]);
    }
    __builtin_amdgcn_wave_barrier();

    // ---- exchange 2 read: b128 whole-f4 units, F = 128ax + 8m2 + (u^(m2&7)) ----
    const int base4 = 128 * ax + 8 * m2;
    const int h3 = m2 & 7;
    #pragma unroll
    for (int u = 0; u < 8; ++u) {
        const int F = base4 + (u ^ h3);
        float4 v1 = lds4[F];
        vr1[2*u] = v1.x; vi1[2*u] = v1.y; vr1[2*u+1] = v1.z; vi1[2*u+1] = v1.w;
        float4 v2 = lds4[2048 + F];
        vr2[2*u] = v2.x; vi2[2*u] = v2.y; vr2[2*u+1] = v2.z; vi2[2*u+1] = v2.w;
    }

    // ---- stage C: DFT16 over m; freq k = 256*r3 + 16*m2 + ax ----
    dft16<false>(vr1, vi1);
    dft16<false>(vr2, vi2);

    // ---- pointwise H[k]/N (coefficients shared by both FFTs) ----
    {
        const int c = (m2 << 4) | ax;            // in [0,255]
        const float sc = 1.0f / 4096.0f;
        #pragma unroll
        for (int r3 = 0; r3 < 4; ++r3) {         // k < 1024: active
            const int k = (r3 << 8) + c;
            const float hr = w_real[k] * sc, hi = w_imag[k] * sc;
            cmul_ip(vr1[r3], vi1[r3], hr, hi);
            cmul_ip(vr2[r3], vi2[r3], hr, hi);
        }
        #pragma unroll
        for (int r3 = 4; r3 < 12; ++r3) {        // truncated band
            vr1[r3] = 0.0f; vi1[r3] = 0.0f;
            vr2[r3] = 0.0f; vi2[r3] = 0.0f;
        }
        {                                        // r3=12: active iff c>0
            const int idx = 1024 - c;
            const float m = (c > 0) ? sc : 0.0f;
            const float hr = w_real[idx] * m, hi = -w_imag[idx] * m;
            cmul_ip(vr1[12], vi1[12], hr, hi);
            cmul_ip(vr2[12], vi2[12], hr, hi);
        }
        #pragma unroll
        for (int r3 = 13; r3 < 16; ++r3) {       // conj mirror
            const int idx = ((16 - r3) << 8) - c;
            const float hr = w_real[idx] * sc, hi = -w_imag[idx] * sc;
            cmul_ip(vr1[r3], vi1[r3], hr, hi);
            cmul_ip(vr2[r3], vi2[r3], hr, hi);
        }
    }

    // ================= inverse: exact adjoint, reverse order =================

    dft16<true>(vr1, vi1);
    dft16<true>(vr2, vi2);

    // ---- exchange 2 reverse write (b128, same F set) ----
    #pragma unroll
    for (int u = 0; u < 8; ++u) {
        const int F = base4 + (u ^ h3);
        lds4[F]        = make_float4(vr1[2*u], vi1[2*u], vr1[2*u+1], vi1[2*u+1]);
        lds4[2048 + F] = make_float4(vr2[2*u], vi2[2*u], vr2[2*u+1], vi2[2*u+1]);
    }
    __builtin_amdgcn_wave_barrier();

    // ---- exchange 2 reverse read (b64 per-thread set) ----
    #pragma unroll
    for (int b = 0; b < 16; ++b) {
        const int ad = bx + 16 * b + 2 * (mh ^ (b & 7));
        float2 v1 = p2[ad];        vr1[b] = v1.x; vi1[b] = v1.y;
        float2 v2 = p2[4096 + ad]; vr2[b] = v2.x; vi2[b] = v2.y;
    }

    // ---- B^H: conj twiddle then conj DFT16 ----
    apply_tw_dual(vr1, vi1, vr2, vi2, cB, -sB);
    dft16<true>(vr1, vi1);
    dft16<true>(vr2, vi2);

    // ---- exchange 1 reverse write (per-thread set) ----
    #pragma unroll
    for (int q = 0; q < 16; ++q) {
        const int ad = bx + 16 * q + 2 * (mh ^ (q & 7));
        p2[ad]        = make_float2(vr1[q], vi1[q]);
        p2[4096 + ad] = make_float2(vr2[q], vi2[q]);
    }
    __syncthreads();

    // ---- exchange 1 reverse read: logical l = 256a + t ----
    #pragma unroll
    for (int a = 0; a < 16; ++a) {
        float2 v1 = p2[256 * a + e1w];        vr1[a] = v1.x; vi1[a] = v1.y;
        float2 v2 = p2[4096 + 256 * a + e1w]; vr2[a] = v2.x; vi2[a] = v2.y;
    }

    // ---- A^H: conj twiddle then conj DFT16 ----
    apply_tw_dual(vr1, vi1, vr2, vi2, cA, -sA);
    dft16<true>(vr1, vi1);
    dft16<true>(vr2, vi2);

    // ---- store 4 rows (nontemporal) ----
    const float bv = bias_p[0];
    float* __restrict__ oa = out + (size_t)(4 * blk) * 4096;
    #pragma unroll
    for (int j = 0; j < 16; ++j) {
        __builtin_nontemporal_store(vr1[j] + bv, &oa[(j << 8) + t]);
        __builtin_nontemporal_store(vi1[j] + bv, &oa[4096 + (j << 8) + t]);
        __builtin_nontemporal_store(vr2[j] + bv, &oa[8192 + (j << 8) + t]);
        __builtin_nontemporal_store(vi2[j] + bv, &oa[12288 + (j << 8) + t]);
    }
}

extern "C" void kernel_launch(void* const* d_in, const int* in_sizes, int n_in,
                              void* d_out, int out_size, void* d_ws, size_t ws_size,
                              hipStream_t stream) {
    (void)in_sizes; (void)n_in; (void)d_ws; (void)ws_size; (void)out_size;
    const float* x      = (const float*)d_in[0];   // (8192, 4096) f32
    const float* w_real = (const float*)d_in[1];   // (2049,) f32
    const float* w_imag = (const float*)d_in[2];   // (2049,) f32
    const float* bias   = (const float*)d_in[3];   // scalar f32
    float* out = (float*)d_out;                    // (8192, 4096) f32

    // 4 rows (= 2 packed complex FFTs) per block
    spectral_circulant_r16x2<<<8192 / 4, NT, 0, stream>>>(x, w_real, w_imag, bias, out);
}